// Round 9
// baseline (387.396 us; speedup 1.0000x reference)
//
#include <hip/hip_runtime.h>

// FlashMHA: B=2, SQ=SK=2048, E=1024, H=16, D=64.  bf16 MFMA, fp32 accum.
//   convert_all: fp32->bf16; biasc = (mask? bias*log2e : -1e30); zeroes the
//                512 attn rendezvous flags (parked in d_out, overwritten by
//                gemm_out's final stores).
//   gemm_qkv: R16: reverted to R13-exact BK=32 single-buffer 2-barrier
//             128x128 grid(32,24).  R10/R12/R14/R15 all failed to beat this
//             simple loop (dbuf, BK=64, more TLP, counted-vmcnt 3-buf): at
//             3 blocks/CU the inter-wave TLP already hides what source-level
//             pipelining would; structural floor ~45us this session.
//   attn_kernel: R9 dbuf gld_lds + XOR swizzle, 1 barrier/chunk, in-register
//                P, bias-as-C-init, MFMA lsum.  R16: combine FUSED via
//                last-block-wins (threadfence + atomicAdd on flags; second
//                arriver of each (bh,qtile) pair normalizes (p0+p1)/(l0+l1)
//                and writes ctx).  combine_kernel deleted.
//   gemm_out: R13 (128x64, BK=64 + swizzle, grid(32,16)) — measured-safe.

using bf16   = __bf16;
using bf16x8 = __attribute__((ext_vector_type(8))) __bf16;
using bf16x4 = __attribute__((ext_vector_type(4))) __bf16;
using f32x4  = __attribute__((ext_vector_type(4))) float;
using i32x2  = __attribute__((ext_vector_type(2))) int;

#define MFMA16x16x32(a, b, c) __builtin_amdgcn_mfma_f32_16x16x32_bf16(a, b, c, 0, 0, 0)

constexpr float LOG2E = 1.4426950408889634f;

__device__ __forceinline__ void gld16(const void* g, void* l) {
  __builtin_amdgcn_global_load_lds(
      (const __attribute__((address_space(1))) unsigned int*)g,
      (__attribute__((address_space(3))) unsigned int*)l, 16, 0, 0);
}

__device__ inline bf16x4 cvt4(float4 v) {
  bf16x4 o;
  o[0] = (bf16)v.x; o[1] = (bf16)v.y; o[2] = (bf16)v.z; o[3] = (bf16)v.w;
  return o;
}

// ---------------------------------------------------------------- convert ---
__global__ __launch_bounds__(256) void convert_all(
    const float4* __restrict__ tgt, const float4* __restrict__ mem,
    const float4* __restrict__ wq,  const float4* __restrict__ wkv,
    const float4* __restrict__ ow,  const float4* __restrict__ bias,
    const int4*   __restrict__ mask,
    bf16x4* __restrict__ tgt_b, bf16x4* __restrict__ mem_b,
    bf16x4* __restrict__ wq_b,  bf16x4* __restrict__ wkv_b,
    bf16x4* __restrict__ ow_b,  float4* __restrict__ biasc,
    int* __restrict__ flags)
{
  long i = (long)blockIdx.x * 256 + threadIdx.x;   // float4 index
  const long T0 = 1048576;            // tgt
  const long T1 = T0 + 1048576;       // mem
  const long T2 = T1 + 262144;        // Wq
  const long T3 = T2 + 524288;        // Wkv
  const long T4 = T3 + 262144;        // out_w
  const long T5 = T4 + 1024;          // bias/mask
  if (i < T0)      { tgt_b[i]      = cvt4(tgt[i]); }
  else if (i < T1) { mem_b[i - T0] = cvt4(mem[i - T0]); }
  else if (i < T2) { wq_b[i - T1]  = cvt4(wq[i - T1]); }
  else if (i < T3) { wkv_b[i - T2] = cvt4(wkv[i - T2]); }
  else if (i < T4) { ow_b[i - T3]  = cvt4(ow[i - T3]); }
  else if (i < T5) {
    long j = i - T4;
    float4 bv = bias[j];
    int4   mv = mask[j];
    float4 o;
    o.x = mv.x ? bv.x * LOG2E : -1e30f;
    o.y = mv.y ? bv.y * LOG2E : -1e30f;
    o.z = mv.z ? bv.z * LOG2E : -1e30f;
    o.w = mv.w ? bv.w * LOG2E : -1e30f;
    biasc[j] = o;
  } else if (i < T5 + 512) {
    flags[i - T5] = 0;                 // attn rendezvous flags (in d_out)
  }
}

// ----------------------------------------------------- merged Q + KV GEMM ---
// R13-exact: BK=32 single-buffer 2-barrier, 128x128, grid(32,24).
__global__ __launch_bounds__(256) void gemm_qkv(
    const bf16* __restrict__ tgt_b, const bf16* __restrict__ mem_b,
    const bf16* __restrict__ wq_b,  const bf16* __restrict__ wkv_b,
    const float* __restrict__ Wq_bias, const float* __restrict__ Wkv_bias,
    bf16* __restrict__ Qb, bf16* __restrict__ Kb, bf16* __restrict__ VTb)
{
  const int tid  = threadIdx.x;
  const int wave = tid >> 6;
  const int lane = tid & 63;
  const int quad = lane >> 4;
  const int l16  = lane & 15;
  const bool isQ = blockIdx.y < 8;
  const bf16*  A    = isQ ? tgt_b : mem_b;
  const bf16*  B    = isQ ? wq_b  : wkv_b;
  const float* bias = isQ ? Wq_bias : Wkv_bias;
  const int m0 = blockIdx.x * 128;
  const int n0 = (isQ ? blockIdx.y : blockIdx.y - 8) * 128;
  const int wm = (wave & 1) * 64;
  const int wn = (wave >> 1) * 64;
  constexpr int K = 1024;

  __shared__ bf16 As[128][32];    // unpadded: required by global_load_lds
  __shared__ bf16 Bs[128][32];

  f32x4 acc[4][4] = {};

  const int srow = lane >> 2;
  const int scol = (lane & 3) * 8;
  const bf16* gA = A + (size_t)(m0 + wave * 16 + srow) * K + scol;
  const bf16* gB = B + (size_t)(n0 + wave * 16 + srow) * K + scol;
  bf16* lA = &As[wave * 16][0];
  bf16* lB = &Bs[wave * 16][0];

  for (int k0 = 0; k0 < K; k0 += 32) {
    __syncthreads();
    gld16(gA + k0, lA);
    gld16(gA + (size_t)64 * K + k0, lA + 64 * 32);
    gld16(gB + k0, lB);
    gld16(gB + (size_t)64 * K + k0, lB + 64 * 32);
    __syncthreads();

    bf16x8 af[4], bfr[4];
#pragma unroll
    for (int i = 0; i < 4; i++)
      af[i] = *(const bf16x8*)(&As[wm + i * 16 + l16][quad * 8]);
#pragma unroll
    for (int j = 0; j < 4; j++)
      bfr[j] = *(const bf16x8*)(&Bs[wn + j * 16 + l16][quad * 8]);
#pragma unroll
    for (int i = 0; i < 4; i++)
#pragma unroll
      for (int j = 0; j < 4; j++)
        acc[i][j] = MFMA16x16x32(af[i], bfr[j], acc[i][j]);
  }

  const float qscale = 0.125f * LOG2E;
#pragma unroll
  for (int i = 0; i < 4; i++) {
    const int row = m0 + wm + i * 16 + quad * 4;
#pragma unroll
    for (int j = 0; j < 4; j++) {
      const int col = n0 + wn + j * 16 + l16;
      const float bv = bias[col];
      if (isQ) {
#pragma unroll
        for (int r = 0; r < 4; r++)
          Qb[(size_t)(row + r) * 1024 + col] = (bf16)((acc[i][j][r] + bv) * qscale);
      } else {
        const int b = row >> 11, s = row & 2047;
        if (col < 1024) {
          const int hh = col >> 6, dd = col & 63;
          bf16* kp = Kb + ((((size_t)b * 16 + hh) * 2048 + s) * 64 + dd);
#pragma unroll
          for (int r = 0; r < 4; r++) kp[(size_t)r * 64] = (bf16)(acc[i][j][r] + bv);
        } else {
          const int vh = (col - 1024) >> 6, vd = (col - 1024) & 63;
          bf16x4 pk;
#pragma unroll
          for (int r = 0; r < 4; r++) pk[r] = (bf16)(acc[i][j][r] + bv);
          *(bf16x4*)(VTb + (((size_t)b * 16 + vh) * 64 + vd) * 2048 + s) = pk;
        }
      }
    }
  }
}

// --------------------------------------------------------------- out GEMM ---
// 128(M) x 64(N) tiles, grid (32,16) = 512 blocks = 2 blocks/CU.
// R13: BK=64 + source-side XOR swizzle.
__global__ __launch_bounds__(256) void gemm_out(
    const bf16* __restrict__ A, const bf16* __restrict__ B,
    const float* __restrict__ bias, float* __restrict__ C)
{
  const int tid  = threadIdx.x;
  const int wave = tid >> 6;
  const int lane = tid & 63;
  const int quad = lane >> 4;
  const int l16  = lane & 15;
  const int m0 = blockIdx.x * 128;
  const int n0 = blockIdx.y * 64;
  const int wm = (wave & 1) * 64;
  const int wn = (wave >> 1) * 32;
  constexpr int K = 1024, N = 1024;

  __shared__ bf16 As[128][64];   // 16 KiB, swizzled content
  __shared__ bf16 Bs[64][64];    //  8 KiB

  f32x4 acc[4][2] = {};

  const int srow  = lane >> 3;
  const int sslot = (lane & 7) ^ srow;
  const bf16* gA = A + (size_t)(m0 + wave * 32 + srow) * K + sslot * 8;
  const bf16* gB = B + (size_t)(n0 + wave * 16 + srow) * K + sslot * 8;
  bf16* lA = &As[wave * 32][0];
  bf16* lB = &Bs[wave * 16][0];

  for (int k0 = 0; k0 < K; k0 += 64) {
    __syncthreads();
#pragma unroll
    for (int j = 0; j < 4; j++)
      gld16(gA + (size_t)(j * 8) * K + k0, lA + j * 512);
#pragma unroll
    for (int j = 0; j < 2; j++)
      gld16(gB + (size_t)(j * 8) * K + k0, lB + j * 512);
    __syncthreads();

#pragma unroll
    for (int kk = 0; kk < 2; kk++) {
      const int rslot = ((quad + kk * 4) ^ (l16 & 7)) * 8;
      bf16x8 af[4], bfr[2];
#pragma unroll
      for (int i = 0; i < 4; i++)
        af[i] = *(const bf16x8*)(&As[wm + i * 16 + l16][rslot]);
#pragma unroll
      for (int j = 0; j < 2; j++)
        bfr[j] = *(const bf16x8*)(&Bs[wn + j * 16 + l16][rslot]);
#pragma unroll
      for (int i = 0; i < 4; i++)
#pragma unroll
        for (int j = 0; j < 2; j++)
          acc[i][j] = MFMA16x16x32(af[i], bfr[j], acc[i][j]);
    }
  }

#pragma unroll
  for (int i = 0; i < 4; i++) {
    const int row = m0 + wm + i * 16 + quad * 4;
#pragma unroll
    for (int j = 0; j < 2; j++) {
      const int col = n0 + wn + j * 16 + l16;
      const float bv = bias[col];
#pragma unroll
      for (int r = 0; r < 4; r++)
        C[(size_t)(row + r) * N + col] = acc[i][j][r] + bv;
    }
  }
}

// -------------------------------------------------------------- attention ---
// Split-K partials; block = (bh, qtile, shalf); 4 waves x 32 q-rows.
// R9 dbuf gld_lds + XOR swizzle; R8 in-register P; R10 bias-as-C-init;
// R11 MFMA lsum; R16 fused combine (last-block-wins per (bh,qtile) pair).
__global__ __launch_bounds__(256, 4) void attn_kernel(
    const bf16* __restrict__ Qb, const bf16* __restrict__ Kb,
    const bf16* __restrict__ VTb, const float* __restrict__ biasc,
    bf16* __restrict__ Pp, float* __restrict__ Ls,
    int* __restrict__ flags, bf16* __restrict__ ctx)
{
  const int tid  = threadIdx.x;
  const int wave = tid >> 6;
  const int lane = tid & 63;
  const int quad = lane >> 4;
  const int l16  = lane & 15;
  const int blk   = blockIdx.x;                   // 0..1023
  const int bh    = (blk & 7) * 4 + (blk >> 8);   // same bh -> same XCD
  const int qtile = (blk >> 3) & 15;
  const int shalf = (blk >> 7) & 1;
  const int bi    = bh >> 4;
  const int h     = bh & 15;

  // [dbuf][K=0/V=1][row][col] linear 64x64, XOR-swizzled content:
  //   KV[b][m][r][slot8] holds M[r][slot8 ^ (r&7)]  (slot8 = 8-bf16 group)
  __shared__ bf16 KV[2][2][64][64];          // 32 KiB
  __shared__ int  winner;

  const int qrow0 = qtile * 128 + wave * 32;
  bf16x8 aq[2][2];
#pragma unroll
  for (int t = 0; t < 2; t++)
#pragma unroll
    for (int k = 0; k < 2; k++)
      aq[t][k] = *(const bf16x8*)(Qb + (size_t)(bi * 2048 + qrow0 + t * 16 + l16) * 1024
                                  + h * 64 + k * 32 + quad * 8);

  bf16x8 ones;
#pragma unroll
  for (int j = 0; j < 8; j++) ones[j] = (bf16)1.0f;

  f32x4 acc[2][4] = {};
  f32x4 lacc[2]   = {};

  const bf16* kbase = Kb  + (size_t)bh * 2048 * 64;
  const bf16* vbase = VTb + (size_t)bh * 64 * 2048;
  const float* bptr = biasc + bi * 2048;

  // staging geometry: wave w + call j cover LDS rows 16w+8j .. +7;
  // lane i -> row 16w+8j+(i>>3), lds slot (i&7); global col slot = lds ^ (row&7)
  const int lr = lane >> 3;                       // 0..7 == row&7 for both calls
  const int lc = ((lane & 7) ^ lr) * 8;           // swizzled source col (bf16)
  const int r0 = wave * 16 + lr;
  const bf16* kg0 = kbase + (size_t)r0 * 64 + lc;         // + soff*64
  const bf16* kg1 = kbase + (size_t)(r0 + 8) * 64 + lc;
  const bf16* vg0 = vbase + (size_t)r0 * 2048 + lc;       // + soff
  const bf16* vg1 = vbase + (size_t)(r0 + 8) * 2048 + lc;

  const int sbeg = shalf * 1024;

  auto issueKV = [&](int buf, int soff) {
    bf16* kd = &KV[buf][0][0][0] + wave * 1024;   // 2 KiB per wave
    bf16* vd = &KV[buf][1][0][0] + wave * 1024;
    gld16(kg0 + (size_t)soff * 64, kd);
    gld16(kg1 + (size_t)soff * 64, kd + 512);
    gld16(vg0 + soff, vd);
    gld16(vg1 + soff, vd + 512);
  };

  issueKV(0, sbeg);

  for (int ci = 0; ci < 16; ci++) {
    // implicit s_waitcnt vmcnt(0): own gld_lds for chunk ci land; barrier
    // makes all waves' writes visible; prior reads of buf^1 are fenced.
    __syncthreads();
    if (ci < 15) issueKV((ci + 1) & 1, sbeg + (ci + 1) * 64);

    const bf16* Kc = &KV[ci & 1][0][0][0];
    const bf16* Vc = &KV[ci & 1][1][0][0];
    const int soff = sbeg + ci * 64;

    // bias for this chunk (lane's s = soff + c*16 + quad*4 + r) — used as
    // the C-initializer of the QK^T MFMA.
    f32x4 bv4[4];
#pragma unroll
    for (int c = 0; c < 4; c++)
      bv4[c] = *(const f32x4*)(bptr + soff + c * 16 + quad * 4);

    // S^T = K Q^T + bias: lane holds S[s = c*16+quad*4+r][q = t*16+l16].
    unsigned int w[2][4][2];
#pragma unroll
    for (int c = 0; c < 4; c++) {
      const int krow = c * 16 + l16;
      const int ks   = l16 & 7;
      bf16x8 b0 = *(const bf16x8*)(Kc + krow * 64 + ((quad) ^ ks) * 8);
      bf16x8 b1 = *(const bf16x8*)(Kc + krow * 64 + ((quad + 4) ^ ks) * 8);
#pragma unroll
      for (int t = 0; t < 2; t++) {
        __builtin_amdgcn_s_setprio(1);
        f32x4 s = MFMA16x16x32(b0, aq[t][0], bv4[c]);
        s = MFMA16x16x32(b1, aq[t][1], s);
        __builtin_amdgcn_s_setprio(0);
        union { bf16x4 h; unsigned int u[2]; } pw;
#pragma unroll
        for (int r = 0; r < 4; r++)
          pw.h[r] = (bf16)__builtin_amdgcn_exp2f(s[r]);
        w[t][c][0] = pw.u[0];
        w[t][c][1] = pw.u[1];
      }
    }

    // V fragments (reused by both q-tiles)
    bf16x8 vb0[4], vb1[4];
#pragma unroll
    for (int db = 0; db < 4; db++) {
      const int vrow = db * 16 + l16;
      const int vs   = l16 & 7;
      vb0[db] = *(const bf16x8*)(Vc + vrow * 64 + ((quad) ^ vs) * 8);
      vb1[db] = *(const bf16x8*)(Vc + vrow * 64 + ((quad + 4) ^ vs) * 8);
    }

    // Redistribute P words to A-fragment layout on the VALU pipe.
#pragma unroll
    for (int t = 0; t < 2; t++) {
      union { unsigned int u[4]; bf16x8 v; } a0, a1;
#pragma unroll
      for (int pr = 0; pr < 2; pr++) {           // 0: s 0..31 (c0,c1), 1: s 32..63
        i32x2 r0p = __builtin_amdgcn_permlane32_swap(
            (int)w[t][pr * 2][0], (int)w[t][pr * 2 + 1][0], false, false);
        i32x2 r1p = __builtin_amdgcn_permlane32_swap(
            (int)w[t][pr * 2][1], (int)w[t][pr * 2 + 1][1], false, false);
        i32x2 l0 = __builtin_amdgcn_permlane16_swap(r0p[0], r0p[1], false, false);
        i32x2 l1 = __builtin_amdgcn_permlane16_swap(r1p[0], r1p[1], false, false);
        unsigned int* du = pr ? a1.u : a0.u;     // pr is unroll-constant
        du[0] = (unsigned int)l0[0];
        du[1] = (unsigned int)l1[0];
        du[2] = (unsigned int)l0[1];
        du[3] = (unsigned int)l1[1];
      }
      __builtin_amdgcn_s_setprio(1);
      lacc[t] = MFMA16x16x32(a0.v, ones, lacc[t]);
      lacc[t] = MFMA16x16x32(a1.v, ones, lacc[t]);
#pragma unroll
      for (int db = 0; db < 4; db++) {
        acc[t][db] = MFMA16x16x32(a0.v, vb0[db], acc[t][db]);
        acc[t][db] = MFMA16x16x32(a1.v, vb1[db], acc[t][db]);
      }
      __builtin_amdgcn_s_setprio(0);
    }
  }

  // lsum store (R7 layout: lacc[t][r] holds rowsum for q-row quad*4+r; all
  // l16 lanes replicate the value)
#pragma unroll
  for (int t = 0; t < 2; t++) {
    const int rowb = bi * 2048 + qrow0 + t * 16 + quad * 4;
#pragma unroll
    for (int r = 0; r < 4; r++)
      if (l16 == 0)
        Ls[shalf * 65536 + (rowb + r) * 16 + h] = lacc[t][r];
  }

  // store raw partials (no normalization here)
#pragma unroll
  for (int t = 0; t < 2; t++) {
    const int rowb = bi * 2048 + qrow0 + t * 16 + quad * 4;
#pragma unroll
    for (int db = 0; db < 4; db++)
#pragma unroll
      for (int r = 0; r < 4; r++)
        Pp[(size_t)shalf * 4194304 + (size_t)(rowb + r) * 1024 + h * 64 + db * 16 + l16]
            = (bf16)acc[t][db][r];
  }

  // ---- fused combine: last block of the (bh,qtile) pair normalizes ----
  // release: every thread fences its own Pp/Ls stores, then block-sync, then
  // one thread bumps the pair flag (threadFenceReduction pattern).
  __threadfence();
  __syncthreads();
  if (tid == 0) winner = atomicAdd(&flags[bh * 16 + qtile], 1);
  __syncthreads();
  if (winner == 1) {
    __threadfence();   // acquire side
    const int rbase = bi * 2048 + qtile * 128;
#pragma unroll
    for (int g4 = 0; g4 < 4; g4++) {
      const int g  = tid * 4 + g4;        // 0..1023 = 128 rows x 8 col-groups
      const int rr = g >> 3;
      const int cc = (g & 7) * 8;
      const int row = rbase + rr;
      const size_t off = (size_t)row * 1024 + h * 64 + cc;
      const bf16x8 p0 = *(const bf16x8*)(Pp + off);
      const bf16x8 p1 = *(const bf16x8*)(Pp + 4194304 + off);
      const float inv = 1.0f / (Ls[row * 16 + h] + Ls[65536 + row * 16 + h]);
      bf16x8 o;
#pragma unroll
      for (int j = 0; j < 8; j++)
        o[j] = (bf16)(((float)p0[j] + (float)p1[j]) * inv);
      *(bf16x8*)(ctx + off) = o;
    }
  }
}

// ----------------------------------------------------------------- launch ---
extern "C" void kernel_launch(void* const* d_in, const int* in_sizes, int n_in,
                              void* d_out, int out_size, void* d_ws, size_t ws_size,
                              hipStream_t stream)
{
  const float* tgt       = (const float*)d_in[0];
  const float* mem       = (const float*)d_in[1];
  const float* attn_bias = (const float*)d_in[2];
  const int*   mask      = (const int*)d_in[3];
  const float* Wq_b      = (const float*)d_in[5];
  const float* Wkv_b     = (const float*)d_in[7];
  const float* out_b     = (const float*)d_in[9];
  float* out = (float*)d_out;

  bf16*  base  = (bf16*)d_ws;
  bf16*  tgt_b = base;
  bf16*  mem_b = tgt_b + 4194304;
  bf16*  wq_b  = mem_b + 4194304;
  bf16*  wkv_b = wq_b + 1048576;
  bf16*  ow_b  = wkv_b + 2097152;
  float* biasc = (float*)(ow_b + 1048576);
  bf16*  Qb    = (bf16*)(biasc + 4096);
  bf16*  Kb    = Qb + 4194304;
  bf16*  VTb   = Kb + 4194304;
  // overlays (regions dead by the time these are written):
  bf16*  Pp    = base;            // partial ctx [2][4096][1024] over tgt_b+mem_b
  float* Ls    = (float*)wq_b;    // partial lsum [2][4096][16] over wq_b
  bf16*  ctxb  = Qb;              // combined ctx over Qb (dead after attn)
  int*   flags = (int*)d_out;     // 512 ints; zeroed by convert, clobbered by gemm_out

  convert_all<<<12294, 256, 0, stream>>>(
      (const float4*)tgt, (const float4*)mem, (const float4*)d_in[4],
      (const float4*)d_in[6], (const float4*)d_in[8], (const float4*)attn_bias,
      (const int4*)mask,
      (bf16x4*)tgt_b, (bf16x4*)mem_b, (bf16x4*)wq_b, (bf16x4*)wkv_b,
      (bf16x4*)ow_b, (float4*)biasc, flags);

  gemm_qkv<<<dim3(32, 24), 256, 0, stream>>>(
      tgt_b, mem_b, wq_b, wkv_b, Wq_b, Wkv_b, Qb, Kb, VTb);
  attn_kernel<<<1024, 256, 0, stream>>>(Qb, Kb, VTb, biasc, Pp, Ls, flags, ctxb);
  gemm_out<<<dim3(32, 16), 256, 0, stream>>>(ctxb, ow_b, out_b, out);
}

// Round 10
// 209.160 us; speedup vs baseline: 1.8522x; 1.8522x over previous
//
#include <hip/hip_runtime.h>

// FlashMHA: B=2, SQ=SK=2048, E=1024, H=16, D=64.  bf16 MFMA, fp32 accum.
//   convert_all: fp32->bf16; biasc = (mask? bias*log2e : -1e30)
//   gemm_qkv: R13 BK=32 single-buffer 2-barrier 128x128 + R17 XCD-aware
//             block swizzle: 1-D grid 768, bid=(c*256+q*8+xcd) -> x=q,
//             y=xcd*3+c, so each XCD's 96 resident blocks cover exactly 3
//             complete B-panels (768KB << 4MB L2): converts ~900cyc HBM
//             misses to ~200cyc L2 hits (kernel is latency-bound at 14% BW,
//             37MB fetched vs 22MB ideal).
//   attn_kernel: R13-exact (R9 dbuf gld_lds + XOR swizzle, 1 barrier/chunk,
//                in-register P, bias-as-C-init, MFMA lsum).  R16's fused
//                combine REVERTED: __threadfence is a device-scope fence ->
//                per-block L2 writeback on non-coherent XCDs; attn 45->242us.
//   combine: restored separate kernel.  ctx = (p0+p1)/(l0+l1) -> bf16
//   gemm_out: R13 (128x64, BK=64 + swizzle) + R17 XCD swizzle (y=xcd*2+c).

using bf16   = __bf16;
using bf16x8 = __attribute__((ext_vector_type(8))) __bf16;
using bf16x4 = __attribute__((ext_vector_type(4))) __bf16;
using f32x4  = __attribute__((ext_vector_type(4))) float;
using i32x2  = __attribute__((ext_vector_type(2))) int;

#define MFMA16x16x32(a, b, c) __builtin_amdgcn_mfma_f32_16x16x32_bf16(a, b, c, 0, 0, 0)

constexpr float LOG2E = 1.4426950408889634f;

__device__ __forceinline__ void gld16(const void* g, void* l) {
  __builtin_amdgcn_global_load_lds(
      (const __attribute__((address_space(1))) unsigned int*)g,
      (__attribute__((address_space(3))) unsigned int*)l, 16, 0, 0);
}

__device__ inline bf16x4 cvt4(float4 v) {
  bf16x4 o;
  o[0] = (bf16)v.x; o[1] = (bf16)v.y; o[2] = (bf16)v.z; o[3] = (bf16)v.w;
  return o;
}

// ---------------------------------------------------------------- convert ---
__global__ __launch_bounds__(256) void convert_all(
    const float4* __restrict__ tgt, const float4* __restrict__ mem,
    const float4* __restrict__ wq,  const float4* __restrict__ wkv,
    const float4* __restrict__ ow,  const float4* __restrict__ bias,
    const int4*   __restrict__ mask,
    bf16x4* __restrict__ tgt_b, bf16x4* __restrict__ mem_b,
    bf16x4* __restrict__ wq_b,  bf16x4* __restrict__ wkv_b,
    bf16x4* __restrict__ ow_b,  float4* __restrict__ biasc)
{
  long i = (long)blockIdx.x * 256 + threadIdx.x;   // float4 index
  const long T0 = 1048576;            // tgt
  const long T1 = T0 + 1048576;       // mem
  const long T2 = T1 + 262144;        // Wq
  const long T3 = T2 + 524288;        // Wkv
  const long T4 = T3 + 262144;        // out_w
  const long T5 = T4 + 1024;          // bias/mask
  if (i < T0)      { tgt_b[i]      = cvt4(tgt[i]); }
  else if (i < T1) { mem_b[i - T0] = cvt4(mem[i - T0]); }
  else if (i < T2) { wq_b[i - T1]  = cvt4(wq[i - T1]); }
  else if (i < T3) { wkv_b[i - T2] = cvt4(wkv[i - T2]); }
  else if (i < T4) { ow_b[i - T3]  = cvt4(ow[i - T3]); }
  else if (i < T5) {
    long j = i - T4;
    float4 bv = bias[j];
    int4   mv = mask[j];
    float4 o;
    o.x = mv.x ? bv.x * LOG2E : -1e30f;
    o.y = mv.y ? bv.y * LOG2E : -1e30f;
    o.z = mv.z ? bv.z * LOG2E : -1e30f;
    o.w = mv.w ? bv.w * LOG2E : -1e30f;
    biasc[j] = o;
  }
}

// ----------------------------------------------------- merged Q + KV GEMM ---
// R13 BK=32 2-barrier.  R17: 1-D grid 768, XCD-aware remap
// bid = c*256 + q*8 + xcd  ->  x = q (0..31), y = xcd*3 + c (0..23).
__global__ __launch_bounds__(256) void gemm_qkv(
    const bf16* __restrict__ tgt_b, const bf16* __restrict__ mem_b,
    const bf16* __restrict__ wq_b,  const bf16* __restrict__ wkv_b,
    const float* __restrict__ Wq_bias, const float* __restrict__ Wkv_bias,
    bf16* __restrict__ Qb, bf16* __restrict__ Kb, bf16* __restrict__ VTb)
{
  const int tid  = threadIdx.x;
  const int wave = tid >> 6;
  const int lane = tid & 63;
  const int quad = lane >> 4;
  const int l16  = lane & 15;

  const int bid  = blockIdx.x;            // 0..767
  const int xcd  = bid & 7;
  const int q    = (bid >> 3) & 31;
  const int cpan = bid >> 8;              // 0..2
  const int bx   = q;
  const int by   = xcd * 3 + cpan;        // 0..23

  const bool isQ = by < 8;
  const bf16*  A    = isQ ? tgt_b : mem_b;
  const bf16*  B    = isQ ? wq_b  : wkv_b;
  const float* bias = isQ ? Wq_bias : Wkv_bias;
  const int m0 = bx * 128;
  const int n0 = (isQ ? by : by - 8) * 128;
  const int wm = (wave & 1) * 64;
  const int wn = (wave >> 1) * 64;
  constexpr int K = 1024;

  __shared__ bf16 As[128][32];    // unpadded: required by global_load_lds
  __shared__ bf16 Bs[128][32];

  f32x4 acc[4][4] = {};

  const int srow = lane >> 2;
  const int scol = (lane & 3) * 8;
  const bf16* gA = A + (size_t)(m0 + wave * 16 + srow) * K + scol;
  const bf16* gB = B + (size_t)(n0 + wave * 16 + srow) * K + scol;
  bf16* lA = &As[wave * 16][0];
  bf16* lB = &Bs[wave * 16][0];

  for (int k0 = 0; k0 < K; k0 += 32) {
    __syncthreads();
    gld16(gA + k0, lA);
    gld16(gA + (size_t)64 * K + k0, lA + 64 * 32);
    gld16(gB + k0, lB);
    gld16(gB + (size_t)64 * K + k0, lB + 64 * 32);
    __syncthreads();

    bf16x8 af[4], bfr[4];
#pragma unroll
    for (int i = 0; i < 4; i++)
      af[i] = *(const bf16x8*)(&As[wm + i * 16 + l16][quad * 8]);
#pragma unroll
    for (int j = 0; j < 4; j++)
      bfr[j] = *(const bf16x8*)(&Bs[wn + j * 16 + l16][quad * 8]);
#pragma unroll
    for (int i = 0; i < 4; i++)
#pragma unroll
      for (int j = 0; j < 4; j++)
        acc[i][j] = MFMA16x16x32(af[i], bfr[j], acc[i][j]);
  }

  const float qscale = 0.125f * LOG2E;
#pragma unroll
  for (int i = 0; i < 4; i++) {
    const int row = m0 + wm + i * 16 + quad * 4;
#pragma unroll
    for (int j = 0; j < 4; j++) {
      const int col = n0 + wn + j * 16 + l16;
      const float bv = bias[col];
      if (isQ) {
#pragma unroll
        for (int r = 0; r < 4; r++)
          Qb[(size_t)(row + r) * 1024 + col] = (bf16)((acc[i][j][r] + bv) * qscale);
      } else {
        const int b = row >> 11, s = row & 2047;
        if (col < 1024) {
          const int hh = col >> 6, dd = col & 63;
          bf16* kp = Kb + ((((size_t)b * 16 + hh) * 2048 + s) * 64 + dd);
#pragma unroll
          for (int r = 0; r < 4; r++) kp[(size_t)r * 64] = (bf16)(acc[i][j][r] + bv);
        } else {
          const int vh = (col - 1024) >> 6, vd = (col - 1024) & 63;
          bf16x4 pk;
#pragma unroll
          for (int r = 0; r < 4; r++) pk[r] = (bf16)(acc[i][j][r] + bv);
          *(bf16x4*)(VTb + (((size_t)b * 16 + vh) * 64 + vd) * 2048 + s) = pk;
        }
      }
    }
  }
}

// --------------------------------------------------------------- out GEMM ---
// 128(M) x 64(N) tiles, 512 blocks (1-D) = 2/CU.  BK=64 + src-side XOR
// swizzle.  R17: XCD remap bid = c*256 + q*8 + xcd -> x=q, y=xcd*2+c.
__global__ __launch_bounds__(256) void gemm_out(
    const bf16* __restrict__ A, const bf16* __restrict__ B,
    const float* __restrict__ bias, float* __restrict__ C)
{
  const int tid  = threadIdx.x;
  const int wave = tid >> 6;
  const int lane = tid & 63;
  const int quad = lane >> 4;
  const int l16  = lane & 15;

  const int bid  = blockIdx.x;            // 0..511
  const int xcd  = bid & 7;
  const int q    = (bid >> 3) & 31;
  const int cpan = bid >> 8;              // 0..1
  const int m0 = q * 128;
  const int n0 = (xcd * 2 + cpan) * 64;

  const int wm = (wave & 1) * 64;
  const int wn = (wave >> 1) * 32;
  constexpr int K = 1024, N = 1024;

  __shared__ bf16 As[128][64];   // 16 KiB, swizzled content
  __shared__ bf16 Bs[64][64];    //  8 KiB

  f32x4 acc[4][2] = {};

  const int srow  = lane >> 3;
  const int sslot = (lane & 7) ^ srow;
  const bf16* gA = A + (size_t)(m0 + wave * 32 + srow) * K + sslot * 8;
  const bf16* gB = B + (size_t)(n0 + wave * 16 + srow) * K + sslot * 8;
  bf16* lA = &As[wave * 32][0];
  bf16* lB = &Bs[wave * 16][0];

  for (int k0 = 0; k0 < K; k0 += 64) {
    __syncthreads();
#pragma unroll
    for (int j = 0; j < 4; j++)
      gld16(gA + (size_t)(j * 8) * K + k0, lA + j * 512);
#pragma unroll
    for (int j = 0; j < 2; j++)
      gld16(gB + (size_t)(j * 8) * K + k0, lB + j * 512);
    __syncthreads();

#pragma unroll
    for (int kk = 0; kk < 2; kk++) {
      const int rslot = ((quad + kk * 4) ^ (l16 & 7)) * 8;
      bf16x8 af[4], bfr[2];
#pragma unroll
      for (int i = 0; i < 4; i++)
        af[i] = *(const bf16x8*)(&As[wm + i * 16 + l16][rslot]);
#pragma unroll
      for (int j = 0; j < 2; j++)
        bfr[j] = *(const bf16x8*)(&Bs[wn + j * 16 + l16][rslot]);
#pragma unroll
      for (int i = 0; i < 4; i++)
#pragma unroll
        for (int j = 0; j < 2; j++)
          acc[i][j] = MFMA16x16x32(af[i], bfr[j], acc[i][j]);
    }
  }

#pragma unroll
  for (int i = 0; i < 4; i++) {
    const int row = m0 + wm + i * 16 + quad * 4;
#pragma unroll
    for (int j = 0; j < 2; j++) {
      const int col = n0 + wn + j * 16 + l16;
      const float bv = bias[col];
#pragma unroll
      for (int r = 0; r < 4; r++)
        C[(size_t)(row + r) * N + col] = acc[i][j][r] + bv;
    }
  }
}

// -------------------------------------------------------------- attention ---
// Split-K partials; block = (bh, qtile, shalf); 4 waves x 32 q-rows.
// R9 dbuf gld_lds + XOR swizzle, one barrier/chunk; R8 in-register P;
// R10 bias-as-C-init; R11 lsum on the MFMA pipe (ones trick, R7 layout).
__global__ __launch_bounds__(256, 4) void attn_kernel(
    const bf16* __restrict__ Qb, const bf16* __restrict__ Kb,
    const bf16* __restrict__ VTb, const float* __restrict__ biasc,
    bf16* __restrict__ Pp, float* __restrict__ Ls)
{
  const int tid  = threadIdx.x;
  const int wave = tid >> 6;
  const int lane = tid & 63;
  const int quad = lane >> 4;
  const int l16  = lane & 15;
  const int blk   = blockIdx.x;                   // 0..1023
  const int bh    = (blk & 7) * 4 + (blk >> 8);   // same bh -> same XCD
  const int qtile = (blk >> 3) & 15;
  const int shalf = (blk >> 7) & 1;
  const int bi    = bh >> 4;
  const int h     = bh & 15;

  // [dbuf][K=0/V=1][row][col] linear 64x64, XOR-swizzled content:
  //   KV[b][m][r][slot8] holds M[r][slot8 ^ (r&7)]  (slot8 = 8-bf16 group)
  __shared__ bf16 KV[2][2][64][64];          // 32 KiB

  const int qrow0 = qtile * 128 + wave * 32;
  bf16x8 aq[2][2];
#pragma unroll
  for (int t = 0; t < 2; t++)
#pragma unroll
    for (int k = 0; k < 2; k++)
      aq[t][k] = *(const bf16x8*)(Qb + (size_t)(bi * 2048 + qrow0 + t * 16 + l16) * 1024
                                  + h * 64 + k * 32 + quad * 8);

  bf16x8 ones;
#pragma unroll
  for (int j = 0; j < 8; j++) ones[j] = (bf16)1.0f;

  f32x4 acc[2][4] = {};
  f32x4 lacc[2]   = {};

  const bf16* kbase = Kb  + (size_t)bh * 2048 * 64;
  const bf16* vbase = VTb + (size_t)bh * 64 * 2048;
  const float* bptr = biasc + bi * 2048;

  // staging geometry: wave w + call j cover LDS rows 16w+8j .. +7;
  // lane i -> row 16w+8j+(i>>3), lds slot (i&7); global col slot = lds ^ (row&7)
  const int lr = lane >> 3;                       // 0..7 == row&7 for both calls
  const int lc = ((lane & 7) ^ lr) * 8;           // swizzled source col (bf16)
  const int r0 = wave * 16 + lr;
  const bf16* kg0 = kbase + (size_t)r0 * 64 + lc;         // + soff*64
  const bf16* kg1 = kbase + (size_t)(r0 + 8) * 64 + lc;
  const bf16* vg0 = vbase + (size_t)r0 * 2048 + lc;       // + soff
  const bf16* vg1 = vbase + (size_t)(r0 + 8) * 2048 + lc;

  const int sbeg = shalf * 1024;

  auto issueKV = [&](int buf, int soff) {
    bf16* kd = &KV[buf][0][0][0] + wave * 1024;   // 2 KiB per wave
    bf16* vd = &KV[buf][1][0][0] + wave * 1024;
    gld16(kg0 + (size_t)soff * 64, kd);
    gld16(kg1 + (size_t)soff * 64, kd + 512);
    gld16(vg0 + soff, vd);
    gld16(vg1 + soff, vd + 512);
  };

  issueKV(0, sbeg);

  for (int ci = 0; ci < 16; ci++) {
    // implicit s_waitcnt vmcnt(0): own gld_lds for chunk ci land; barrier
    // makes all waves' writes visible; prior reads of buf^1 are fenced.
    __syncthreads();
    if (ci < 15) issueKV((ci + 1) & 1, sbeg + (ci + 1) * 64);

    const bf16* Kc = &KV[ci & 1][0][0][0];
    const bf16* Vc = &KV[ci & 1][1][0][0];
    const int soff = sbeg + ci * 64;

    // bias for this chunk (lane's s = soff + c*16 + quad*4 + r) — used as
    // the C-initializer of the QK^T MFMA.
    f32x4 bv4[4];
#pragma unroll
    for (int c = 0; c < 4; c++)
      bv4[c] = *(const f32x4*)(bptr + soff + c * 16 + quad * 4);

    // S^T = K Q^T + bias: lane holds S[s = c*16+quad*4+r][q = t*16+l16].
    unsigned int w[2][4][2];
#pragma unroll
    for (int c = 0; c < 4; c++) {
      const int krow = c * 16 + l16;
      const int ks   = l16 & 7;
      bf16x8 b0 = *(const bf16x8*)(Kc + krow * 64 + ((quad) ^ ks) * 8);
      bf16x8 b1 = *(const bf16x8*)(Kc + krow * 64 + ((quad + 4) ^ ks) * 8);
#pragma unroll
      for (int t = 0; t < 2; t++) {
        __builtin_amdgcn_s_setprio(1);
        f32x4 s = MFMA16x16x32(b0, aq[t][0], bv4[c]);
        s = MFMA16x16x32(b1, aq[t][1], s);
        __builtin_amdgcn_s_setprio(0);
        union { bf16x4 h; unsigned int u[2]; } pw;
#pragma unroll
        for (int r = 0; r < 4; r++)
          pw.h[r] = (bf16)__builtin_amdgcn_exp2f(s[r]);
        w[t][c][0] = pw.u[0];
        w[t][c][1] = pw.u[1];
      }
    }

    // V fragments (reused by both q-tiles)
    bf16x8 vb0[4], vb1[4];
#pragma unroll
    for (int db = 0; db < 4; db++) {
      const int vrow = db * 16 + l16;
      const int vs   = l16 & 7;
      vb0[db] = *(const bf16x8*)(Vc + vrow * 64 + ((quad) ^ vs) * 8);
      vb1[db] = *(const bf16x8*)(Vc + vrow * 64 + ((quad + 4) ^ vs) * 8);
    }

    // Redistribute P words to A-fragment layout on the VALU pipe.
#pragma unroll
    for (int t = 0; t < 2; t++) {
      union { unsigned int u[4]; bf16x8 v; } a0, a1;
#pragma unroll
      for (int pr = 0; pr < 2; pr++) {           // 0: s 0..31 (c0,c1), 1: s 32..63
        i32x2 r0p = __builtin_amdgcn_permlane32_swap(
            (int)w[t][pr * 2][0], (int)w[t][pr * 2 + 1][0], false, false);
        i32x2 r1p = __builtin_amdgcn_permlane32_swap(
            (int)w[t][pr * 2][1], (int)w[t][pr * 2 + 1][1], false, false);
        i32x2 l0 = __builtin_amdgcn_permlane16_swap(r0p[0], r0p[1], false, false);
        i32x2 l1 = __builtin_amdgcn_permlane16_swap(r1p[0], r1p[1], false, false);
        unsigned int* du = pr ? a1.u : a0.u;     // pr is unroll-constant
        du[0] = (unsigned int)l0[0];
        du[1] = (unsigned int)l1[0];
        du[2] = (unsigned int)l0[1];
        du[3] = (unsigned int)l1[1];
      }
      __builtin_amdgcn_s_setprio(1);
      lacc[t] = MFMA16x16x32(a0.v, ones, lacc[t]);
      lacc[t] = MFMA16x16x32(a1.v, ones, lacc[t]);
#pragma unroll
      for (int db = 0; db < 4; db++) {
        acc[t][db] = MFMA16x16x32(a0.v, vb0[db], acc[t][db]);
        acc[t][db] = MFMA16x16x32(a1.v, vb1[db], acc[t][db]);
      }
      __builtin_amdgcn_s_setprio(0);
    }
  }

  // lsum store (R7 layout: lacc[t][r] holds rowsum for q-row quad*4+r; all
  // l16 lanes replicate the value)
#pragma unroll
  for (int t = 0; t < 2; t++) {
    const int rowb = bi * 2048 + qrow0 + t * 16 + quad * 4;
#pragma unroll
    for (int r = 0; r < 4; r++)
      if (l16 == 0)
        Ls[shalf * 65536 + (rowb + r) * 16 + h] = lacc[t][r];
  }

  // store raw partials (no normalization here)
#pragma unroll
  for (int t = 0; t < 2; t++) {
    const int rowb = bi * 2048 + qrow0 + t * 16 + quad * 4;
#pragma unroll
    for (int db = 0; db < 4; db++)
#pragma unroll
      for (int r = 0; r < 4; r++)
        Pp[(size_t)shalf * 4194304 + (size_t)(rowb + r) * 1024 + h * 64 + db * 16 + l16]
            = (bf16)acc[t][db][r];
  }
}

// ---------------------------------------------------------------- combine ---
__global__ __launch_bounds__(256) void combine_kernel(
    const bf16* __restrict__ Pp, const float* __restrict__ Ls,
    bf16* __restrict__ ctx)
{
  const int t   = blockIdx.x * 256 + threadIdx.x;   // 0..524287
  const int row = t >> 7;
  const int g   = t & 127;
  const int h   = g >> 3;
  const bf16x8 p0 = *(const bf16x8*)(Pp + (size_t)row * 1024 + g * 8);
  const bf16x8 p1 = *(const bf16x8*)(Pp + 4194304 + (size_t)row * 1024 + g * 8);
  const float inv = 1.0f / (Ls[row * 16 + h] + Ls[65536 + row * 16 + h]);
  bf16x8 o;
#pragma unroll
  for (int j = 0; j < 8; j++)
    o[j] = (bf16)(((float)p0[j] + (float)p1[j]) * inv);
  *(bf16x8*)(ctx + (size_t)row * 1024 + g * 8) = o;
}

// ----------------------------------------------------------------- launch ---
extern "C" void kernel_launch(void* const* d_in, const int* in_sizes, int n_in,
                              void* d_out, int out_size, void* d_ws, size_t ws_size,
                              hipStream_t stream)
{
  const float* tgt       = (const float*)d_in[0];
  const float* mem       = (const float*)d_in[1];
  const float* attn_bias = (const float*)d_in[2];
  const int*   mask      = (const int*)d_in[3];
  const float* Wq_b      = (const float*)d_in[5];
  const float* Wkv_b     = (const float*)d_in[7];
  const float* out_b     = (const float*)d_in[9];
  float* out = (float*)d_out;

  bf16*  base  = (bf16*)d_ws;
  bf16*  tgt_b = base;
  bf16*  mem_b = tgt_b + 4194304;
  bf16*  wq_b  = mem_b + 4194304;
  bf16*  wkv_b = wq_b + 1048576;
  bf16*  ow_b  = wkv_b + 2097152;
  float* biasc = (float*)(ow_b + 1048576);
  bf16*  Qb    = (bf16*)(biasc + 4096);
  bf16*  Kb    = Qb + 4194304;
  bf16*  VTb   = Kb + 4194304;
  // overlays (regions dead by the time these are written):
  bf16*  Pp    = base;            // partial ctx [2][4096][1024] over tgt_b+mem_b
  float* Ls    = (float*)wq_b;    // partial lsum [2][4096][16] over wq_b
  bf16*  ctxb  = Qb;              // combined ctx over Qb (dead after attn)

  convert_all<<<12292, 256, 0, stream>>>(
      (const float4*)tgt, (const float4*)mem, (const float4*)d_in[4],
      (const float4*)d_in[6], (const float4*)d_in[8], (const float4*)attn_bias,
      (const int4*)mask,
      (bf16x4*)tgt_b, (bf16x4*)mem_b, (bf16x4*)wq_b, (bf16x4*)wkv_b,
      (bf16x4*)ow_b, (float4*)biasc);

  gemm_qkv<<<768, 256, 0, stream>>>(
      tgt_b, mem_b, wq_b, wkv_b, Wq_b, Wkv_b, Qb, Kb, VTb);
  attn_kernel<<<1024, 256, 0, stream>>>(Qb, Kb, VTb, biasc, Pp, Ls);
  combine_kernel<<<2048, 256, 0, stream>>>(Pp, Ls, ctxb);
  gemm_out<<<512, 256, 0, stream>>>(ctxb, ow_b, out_b, out);
}

// Round 11
// 198.326 us; speedup vs baseline: 1.9533x; 1.0546x over previous
//
#include <hip/hip_runtime.h>

// FlashMHA: B=2, SQ=SK=2048, E=1024, H=16, D=64.  bf16 MFMA, fp32 accum.
//   convert_all: fp32->bf16; biasc = (mask? bias*log2e : -1e30)
//   gemm_qkv: R13-exact BK=32 single-buffer 2-barrier 128x128 grid(32,24).
//             R17's XCD remap REVERTED (-6us: default x-fastest round-robin
//             already gives 8x A-row L2 reuse per XCD; the remap streamed all
//             of A (8MB > 4MB L2) per XCD to gain B locality it didn't need).
//   attn_kernel: R18: NO split-K.  Each block owns (bh, 128-row qtile) over
//                the FULL S=2048 (32 chunks), grid 512 = 2/CU (measured
//                effective residency was only ~2.5 anyway).  Normalizes
//                in-register (inv = 1/lacc) and writes ctx bf16 directly.
//                Eliminates Pp (16MB W) + combine (17MB R + 8MB W + kernel +
//                gap) + Ls.  Core chunk loop unchanged from R13 (R9 dbuf
//                gld_lds + XOR swizzle, 1 barrier/chunk, in-register P,
//                bias-as-C-init, MFMA lsum).
//   gemm_out: R13-exact (128x64, BK=64 + swizzle, grid(32,16)).

using bf16   = __bf16;
using bf16x8 = __attribute__((ext_vector_type(8))) __bf16;
using bf16x4 = __attribute__((ext_vector_type(4))) __bf16;
using f32x4  = __attribute__((ext_vector_type(4))) float;
using i32x2  = __attribute__((ext_vector_type(2))) int;

#define MFMA16x16x32(a, b, c) __builtin_amdgcn_mfma_f32_16x16x32_bf16(a, b, c, 0, 0, 0)

constexpr float LOG2E = 1.4426950408889634f;

__device__ __forceinline__ void gld16(const void* g, void* l) {
  __builtin_amdgcn_global_load_lds(
      (const __attribute__((address_space(1))) unsigned int*)g,
      (__attribute__((address_space(3))) unsigned int*)l, 16, 0, 0);
}

__device__ inline bf16x4 cvt4(float4 v) {
  bf16x4 o;
  o[0] = (bf16)v.x; o[1] = (bf16)v.y; o[2] = (bf16)v.z; o[3] = (bf16)v.w;
  return o;
}

// ---------------------------------------------------------------- convert ---
__global__ __launch_bounds__(256) void convert_all(
    const float4* __restrict__ tgt, const float4* __restrict__ mem,
    const float4* __restrict__ wq,  const float4* __restrict__ wkv,
    const float4* __restrict__ ow,  const float4* __restrict__ bias,
    const int4*   __restrict__ mask,
    bf16x4* __restrict__ tgt_b, bf16x4* __restrict__ mem_b,
    bf16x4* __restrict__ wq_b,  bf16x4* __restrict__ wkv_b,
    bf16x4* __restrict__ ow_b,  float4* __restrict__ biasc)
{
  long i = (long)blockIdx.x * 256 + threadIdx.x;   // float4 index
  const long T0 = 1048576;            // tgt
  const long T1 = T0 + 1048576;       // mem
  const long T2 = T1 + 262144;        // Wq
  const long T3 = T2 + 524288;        // Wkv
  const long T4 = T3 + 262144;        // out_w
  const long T5 = T4 + 1024;          // bias/mask
  if (i < T0)      { tgt_b[i]      = cvt4(tgt[i]); }
  else if (i < T1) { mem_b[i - T0] = cvt4(mem[i - T0]); }
  else if (i < T2) { wq_b[i - T1]  = cvt4(wq[i - T1]); }
  else if (i < T3) { wkv_b[i - T2] = cvt4(wkv[i - T2]); }
  else if (i < T4) { ow_b[i - T3]  = cvt4(ow[i - T3]); }
  else if (i < T5) {
    long j = i - T4;
    float4 bv = bias[j];
    int4   mv = mask[j];
    float4 o;
    o.x = mv.x ? bv.x * LOG2E : -1e30f;
    o.y = mv.y ? bv.y * LOG2E : -1e30f;
    o.z = mv.z ? bv.z * LOG2E : -1e30f;
    o.w = mv.w ? bv.w * LOG2E : -1e30f;
    biasc[j] = o;
  }
}

// ----------------------------------------------------- merged Q + KV GEMM ---
// R13-exact: BK=32 single-buffer 2-barrier, 128x128, grid(32,24).
__global__ __launch_bounds__(256) void gemm_qkv(
    const bf16* __restrict__ tgt_b, const bf16* __restrict__ mem_b,
    const bf16* __restrict__ wq_b,  const bf16* __restrict__ wkv_b,
    const float* __restrict__ Wq_bias, const float* __restrict__ Wkv_bias,
    bf16* __restrict__ Qb, bf16* __restrict__ Kb, bf16* __restrict__ VTb)
{
  const int tid  = threadIdx.x;
  const int wave = tid >> 6;
  const int lane = tid & 63;
  const int quad = lane >> 4;
  const int l16  = lane & 15;
  const bool isQ = blockIdx.y < 8;
  const bf16*  A    = isQ ? tgt_b : mem_b;
  const bf16*  B    = isQ ? wq_b  : wkv_b;
  const float* bias = isQ ? Wq_bias : Wkv_bias;
  const int m0 = blockIdx.x * 128;
  const int n0 = (isQ ? blockIdx.y : blockIdx.y - 8) * 128;
  const int wm = (wave & 1) * 64;
  const int wn = (wave >> 1) * 64;
  constexpr int K = 1024;

  __shared__ bf16 As[128][32];    // unpadded: required by global_load_lds
  __shared__ bf16 Bs[128][32];

  f32x4 acc[4][4] = {};

  const int srow = lane >> 2;
  const int scol = (lane & 3) * 8;
  const bf16* gA = A + (size_t)(m0 + wave * 16 + srow) * K + scol;
  const bf16* gB = B + (size_t)(n0 + wave * 16 + srow) * K + scol;
  bf16* lA = &As[wave * 16][0];
  bf16* lB = &Bs[wave * 16][0];

  for (int k0 = 0; k0 < K; k0 += 32) {
    __syncthreads();
    gld16(gA + k0, lA);
    gld16(gA + (size_t)64 * K + k0, lA + 64 * 32);
    gld16(gB + k0, lB);
    gld16(gB + (size_t)64 * K + k0, lB + 64 * 32);
    __syncthreads();

    bf16x8 af[4], bfr[4];
#pragma unroll
    for (int i = 0; i < 4; i++)
      af[i] = *(const bf16x8*)(&As[wm + i * 16 + l16][quad * 8]);
#pragma unroll
    for (int j = 0; j < 4; j++)
      bfr[j] = *(const bf16x8*)(&Bs[wn + j * 16 + l16][quad * 8]);
#pragma unroll
    for (int i = 0; i < 4; i++)
#pragma unroll
      for (int j = 0; j < 4; j++)
        acc[i][j] = MFMA16x16x32(af[i], bfr[j], acc[i][j]);
  }

  const float qscale = 0.125f * LOG2E;
#pragma unroll
  for (int i = 0; i < 4; i++) {
    const int row = m0 + wm + i * 16 + quad * 4;
#pragma unroll
    for (int j = 0; j < 4; j++) {
      const int col = n0 + wn + j * 16 + l16;
      const float bv = bias[col];
      if (isQ) {
#pragma unroll
        for (int r = 0; r < 4; r++)
          Qb[(size_t)(row + r) * 1024 + col] = (bf16)((acc[i][j][r] + bv) * qscale);
      } else {
        const int b = row >> 11, s = row & 2047;
        if (col < 1024) {
          const int hh = col >> 6, dd = col & 63;
          bf16* kp = Kb + ((((size_t)b * 16 + hh) * 2048 + s) * 64 + dd);
#pragma unroll
          for (int r = 0; r < 4; r++) kp[(size_t)r * 64] = (bf16)(acc[i][j][r] + bv);
        } else {
          const int vh = (col - 1024) >> 6, vd = (col - 1024) & 63;
          bf16x4 pk;
#pragma unroll
          for (int r = 0; r < 4; r++) pk[r] = (bf16)(acc[i][j][r] + bv);
          *(bf16x4*)(VTb + (((size_t)b * 16 + vh) * 64 + vd) * 2048 + s) = pk;
        }
      }
    }
  }
}

// --------------------------------------------------------------- out GEMM ---
// 128(M) x 64(N) tiles, grid (32,16) = 512 blocks = 2 blocks/CU.
// R13: BK=64 + source-side XOR swizzle.
__global__ __launch_bounds__(256) void gemm_out(
    const bf16* __restrict__ A, const bf16* __restrict__ B,
    const float* __restrict__ bias, float* __restrict__ C)
{
  const int tid  = threadIdx.x;
  const int wave = tid >> 6;
  const int lane = tid & 63;
  const int quad = lane >> 4;
  const int l16  = lane & 15;
  const int m0 = blockIdx.x * 128;
  const int n0 = blockIdx.y * 64;
  const int wm = (wave & 1) * 64;
  const int wn = (wave >> 1) * 32;
  constexpr int K = 1024, N = 1024;

  __shared__ bf16 As[128][64];   // 16 KiB, swizzled content
  __shared__ bf16 Bs[64][64];    //  8 KiB

  f32x4 acc[4][2] = {};

  const int srow  = lane >> 3;
  const int sslot = (lane & 7) ^ srow;
  const bf16* gA = A + (size_t)(m0 + wave * 32 + srow) * K + sslot * 8;
  const bf16* gB = B + (size_t)(n0 + wave * 16 + srow) * K + sslot * 8;
  bf16* lA = &As[wave * 32][0];
  bf16* lB = &Bs[wave * 16][0];

  for (int k0 = 0; k0 < K; k0 += 64) {
    __syncthreads();
#pragma unroll
    for (int j = 0; j < 4; j++)
      gld16(gA + (size_t)(j * 8) * K + k0, lA + j * 512);
#pragma unroll
    for (int j = 0; j < 2; j++)
      gld16(gB + (size_t)(j * 8) * K + k0, lB + j * 512);
    __syncthreads();

#pragma unroll
    for (int kk = 0; kk < 2; kk++) {
      const int rslot = ((quad + kk * 4) ^ (l16 & 7)) * 8;
      bf16x8 af[4], bfr[2];
#pragma unroll
      for (int i = 0; i < 4; i++)
        af[i] = *(const bf16x8*)(&As[wm + i * 16 + l16][rslot]);
#pragma unroll
      for (int j = 0; j < 2; j++)
        bfr[j] = *(const bf16x8*)(&Bs[wn + j * 16 + l16][rslot]);
#pragma unroll
      for (int i = 0; i < 4; i++)
#pragma unroll
        for (int j = 0; j < 2; j++)
          acc[i][j] = MFMA16x16x32(af[i], bfr[j], acc[i][j]);
    }
  }

#pragma unroll
  for (int i = 0; i < 4; i++) {
    const int row = m0 + wm + i * 16 + quad * 4;
#pragma unroll
    for (int j = 0; j < 2; j++) {
      const int col = n0 + wn + j * 16 + l16;
      const float bv = bias[col];
#pragma unroll
      for (int r = 0; r < 4; r++)
        C[(size_t)(row + r) * N + col] = acc[i][j][r] + bv;
    }
  }
}

// -------------------------------------------------------------- attention ---
// R18: full-S blocks, no split-K.  block = (bh, qtile); 4 waves x 32 q-rows;
// 32 chunks of 64 s.  Normalized ctx written directly (inv = 1/lacc).
// Core chunk loop: R9 dbuf gld_lds + XOR swizzle, 1 barrier/chunk,
// in-register P (swapped QK^T + permlane), bias-as-C-init, MFMA lsum.
__global__ __launch_bounds__(256, 4) void attn_kernel(
    const bf16* __restrict__ Qb, const bf16* __restrict__ Kb,
    const bf16* __restrict__ VTb, const float* __restrict__ biasc,
    bf16* __restrict__ ctx)
{
  const int tid  = threadIdx.x;
  const int wave = tid >> 6;
  const int lane = tid & 63;
  const int quad = lane >> 4;
  const int l16  = lane & 15;
  const int blk   = blockIdx.x;                   // 0..511
  const int bh    = (blk & 7) * 4 + (blk >> 7);   // same bh -> same XCD
  const int qtile = (blk >> 3) & 15;
  const int bi    = bh >> 4;
  const int h     = bh & 15;

  // [dbuf][K=0/V=1][row][col] linear 64x64, XOR-swizzled content:
  //   KV[b][m][r][slot8] holds M[r][slot8 ^ (r&7)]  (slot8 = 8-bf16 group)
  __shared__ bf16 KV[2][2][64][64];          // 32 KiB

  const int qrow0 = qtile * 128 + wave * 32;
  bf16x8 aq[2][2];
#pragma unroll
  for (int t = 0; t < 2; t++)
#pragma unroll
    for (int k = 0; k < 2; k++)
      aq[t][k] = *(const bf16x8*)(Qb + (size_t)(bi * 2048 + qrow0 + t * 16 + l16) * 1024
                                  + h * 64 + k * 32 + quad * 8);

  bf16x8 ones;
#pragma unroll
  for (int j = 0; j < 8; j++) ones[j] = (bf16)1.0f;

  f32x4 acc[2][4] = {};
  f32x4 lacc[2]   = {};

  const bf16* kbase = Kb  + (size_t)bh * 2048 * 64;
  const bf16* vbase = VTb + (size_t)bh * 64 * 2048;
  const float* bptr = biasc + bi * 2048;

  // staging geometry: wave w + call j cover LDS rows 16w+8j .. +7;
  // lane i -> row 16w+8j+(i>>3), lds slot (i&7); global col slot = lds ^ (row&7)
  const int lr = lane >> 3;                       // 0..7 == row&7 for both calls
  const int lc = ((lane & 7) ^ lr) * 8;           // swizzled source col (bf16)
  const int r0 = wave * 16 + lr;
  const bf16* kg0 = kbase + (size_t)r0 * 64 + lc;         // + soff*64
  const bf16* kg1 = kbase + (size_t)(r0 + 8) * 64 + lc;
  const bf16* vg0 = vbase + (size_t)r0 * 2048 + lc;       // + soff
  const bf16* vg1 = vbase + (size_t)(r0 + 8) * 2048 + lc;

  auto issueKV = [&](int buf, int soff) {
    bf16* kd = &KV[buf][0][0][0] + wave * 1024;   // 2 KiB per wave
    bf16* vd = &KV[buf][1][0][0] + wave * 1024;
    gld16(kg0 + (size_t)soff * 64, kd);
    gld16(kg1 + (size_t)soff * 64, kd + 512);
    gld16(vg0 + soff, vd);
    gld16(vg1 + soff, vd + 512);
  };

  issueKV(0, 0);

  for (int ci = 0; ci < 32; ci++) {
    // implicit s_waitcnt vmcnt(0): own gld_lds for chunk ci land; barrier
    // makes all waves' writes visible; prior reads of buf^1 are fenced.
    __syncthreads();
    if (ci < 31) issueKV((ci + 1) & 1, (ci + 1) * 64);

    const bf16* Kc = &KV[ci & 1][0][0][0];
    const bf16* Vc = &KV[ci & 1][1][0][0];
    const int soff = ci * 64;

    // bias for this chunk (lane's s = soff + c*16 + quad*4 + r) — used as
    // the C-initializer of the QK^T MFMA.
    f32x4 bv4[4];
#pragma unroll
    for (int c = 0; c < 4; c++)
      bv4[c] = *(const f32x4*)(bptr + soff + c * 16 + quad * 4);

    // S^T = K Q^T + bias: lane holds S[s = soff+c*16+quad*4+r][q = t*16+l16].
    unsigned int w[2][4][2];
#pragma unroll
    for (int c = 0; c < 4; c++) {
      const int krow = c * 16 + l16;
      const int ks   = l16 & 7;
      bf16x8 b0 = *(const bf16x8*)(Kc + krow * 64 + ((quad) ^ ks) * 8);
      bf16x8 b1 = *(const bf16x8*)(Kc + krow * 64 + ((quad + 4) ^ ks) * 8);
#pragma unroll
      for (int t = 0; t < 2; t++) {
        __builtin_amdgcn_s_setprio(1);
        f32x4 s = MFMA16x16x32(b0, aq[t][0], bv4[c]);
        s = MFMA16x16x32(b1, aq[t][1], s);
        __builtin_amdgcn_s_setprio(0);
        union { bf16x4 hh; unsigned int u[2]; } pw;
#pragma unroll
        for (int r = 0; r < 4; r++)
          pw.hh[r] = (bf16)__builtin_amdgcn_exp2f(s[r]);
        w[t][c][0] = pw.u[0];
        w[t][c][1] = pw.u[1];
      }
    }

    // V fragments (reused by both q-tiles)
    bf16x8 vb0[4], vb1[4];
#pragma unroll
    for (int db = 0; db < 4; db++) {
      const int vrow = db * 16 + l16;
      const int vs   = l16 & 7;
      vb0[db] = *(const bf16x8*)(Vc + vrow * 64 + ((quad) ^ vs) * 8);
      vb1[db] = *(const bf16x8*)(Vc + vrow * 64 + ((quad + 4) ^ vs) * 8);
    }

    // Redistribute P words to A-fragment layout on the VALU pipe.
#pragma unroll
    for (int t = 0; t < 2; t++) {
      union { unsigned int u[4]; bf16x8 v; } a0, a1;
#pragma unroll
      for (int pr = 0; pr < 2; pr++) {           // 0: s 0..31 (c0,c1), 1: s 32..63
        i32x2 r0p = __builtin_amdgcn_permlane32_swap(
            (int)w[t][pr * 2][0], (int)w[t][pr * 2 + 1][0], false, false);
        i32x2 r1p = __builtin_amdgcn_permlane32_swap(
            (int)w[t][pr * 2][1], (int)w[t][pr * 2 + 1][1], false, false);
        i32x2 l0 = __builtin_amdgcn_permlane16_swap(r0p[0], r0p[1], false, false);
        i32x2 l1 = __builtin_amdgcn_permlane16_swap(r1p[0], r1p[1], false, false);
        unsigned int* du = pr ? a1.u : a0.u;     // pr is unroll-constant
        du[0] = (unsigned int)l0[0];
        du[1] = (unsigned int)l1[0];
        du[2] = (unsigned int)l0[1];
        du[3] = (unsigned int)l1[1];
      }
      __builtin_amdgcn_s_setprio(1);
      lacc[t] = MFMA16x16x32(a0.v, ones, lacc[t]);
      lacc[t] = MFMA16x16x32(a1.v, ones, lacc[t]);
#pragma unroll
      for (int db = 0; db < 4; db++) {
        acc[t][db] = MFMA16x16x32(a0.v, vb0[db], acc[t][db]);
        acc[t][db] = MFMA16x16x32(a1.v, vb1[db], acc[t][db]);
      }
      __builtin_amdgcn_s_setprio(0);
    }
  }

  // normalize in-register and write ctx directly (overlay on Qb is race-free:
  // block (bi,h,qtile) writes exactly the (rows, h-cols) rectangle only it
  // reads, and reads happen at block start before any writes).
#pragma unroll
  for (int t = 0; t < 2; t++) {
    f32x4 inv;
#pragma unroll
    for (int r = 0; r < 4; r++) inv[r] = 1.0f / lacc[t][r];
    const int rowb = bi * 2048 + qrow0 + t * 16 + quad * 4;
#pragma unroll
    for (int db = 0; db < 4; db++)
#pragma unroll
      for (int r = 0; r < 4; r++)
        ctx[(size_t)(rowb + r) * 1024 + h * 64 + db * 16 + l16]
            = (bf16)(acc[t][db][r] * inv[r]);
  }
}

// ----------------------------------------------------------------- launch ---
extern "C" void kernel_launch(void* const* d_in, const int* in_sizes, int n_in,
                              void* d_out, int out_size, void* d_ws, size_t ws_size,
                              hipStream_t stream)
{
  const float* tgt       = (const float*)d_in[0];
  const float* mem       = (const float*)d_in[1];
  const float* attn_bias = (const float*)d_in[2];
  const int*   mask      = (const int*)d_in[3];
  const float* Wq_b      = (const float*)d_in[5];
  const float* Wkv_b     = (const float*)d_in[7];
  const float* out_b     = (const float*)d_in[9];
  float* out = (float*)d_out;

  bf16*  base  = (bf16*)d_ws;
  bf16*  tgt_b = base;
  bf16*  mem_b = tgt_b + 4194304;
  bf16*  wq_b  = mem_b + 4194304;
  bf16*  wkv_b = wq_b + 1048576;
  bf16*  ow_b  = wkv_b + 2097152;
  float* biasc = (float*)(ow_b + 1048576);
  bf16*  Qb    = (bf16*)(biasc + 4096);
  bf16*  Kb    = Qb + 4194304;
  bf16*  VTb   = Kb + 4194304;
  bf16*  ctxb  = Qb;              // ctx overlays Qb (per-block disjoint rects)

  convert_all<<<12292, 256, 0, stream>>>(
      (const float4*)tgt, (const float4*)mem, (const float4*)d_in[4],
      (const float4*)d_in[6], (const float4*)d_in[8], (const float4*)attn_bias,
      (const int4*)mask,
      (bf16x4*)tgt_b, (bf16x4*)mem_b, (bf16x4*)wq_b, (bf16x4*)wkv_b,
      (bf16x4*)ow_b, (float4*)biasc);

  gemm_qkv<<<dim3(32, 24), 256, 0, stream>>>(
      tgt_b, mem_b, wq_b, wkv_b, Wq_b, Wkv_b, Qb, Kb, VTb);
  attn_kernel<<<512, 256, 0, stream>>>(Qb, Kb, VTb, biasc, ctxb);
  gemm_out<<<dim3(32, 16), 256, 0, stream>>>(ctxb, ow_b, out_b, out);
}